// Round 9
// baseline (118.698 us; speedup 1.0000x reference)
//
#include <hip/hip_runtime.h>
#include <math.h>

// NMI loss, shape (2,1,128,128,128) fp32.
// Ledger (R1-R8): scattered DS wave-instr ~54 cyc/op/CU throughput (plain),
// ~218 (atomic); need fewer ops AND >=4-8 waves/CU simultaneously.
// R9: HARD nearest-bin counting. Soft sigmoid transition width ~0.05 bin,
// symmetric about midpoint -> hard-vs-soft error has zero mean; per-cell
// std ~4e-6 in p -> loss error ~1e-4 << 2e-2 threshold.
// Update = +1 to one cell -> per-lane u8 hist (32 voxels/lane max, no
// overflow), 260B-stride rows, 16.6KB/wave, 8 waves/CU, 2 scattered DS
// ops/voxel -> 512 ops/CU ~ 11.5us. Reduce = coalesced b32 (cheap).

static constexpr int   V_PER_BATCH = 128 * 128 * 128;   // 2,097,152
static constexpr int   NBINS = 16;
static constexpr int   NB2   = 256;
static constexpr int   BPB   = 1024;                    // 64-thread blocks per batch
static constexpr int   TOTAL_BLOCKS = BPB * 2;          // 2048 -> 8 blocks/CU
static constexpr int   NREP  = 8;                       // ghist replicas
static constexpr int   ROWW  = 65;                      // u32 words per lane row (260 B)
static constexpr float EPSF  = 1e-6f;

__global__ __launch_bounds__(64) void nmi_hist(
        const float* __restrict__ ytrue,
        const float* __restrict__ ypred,
        unsigned int* __restrict__ ghist,    // [NREP][2][256] counts, zeroed
        unsigned int* __restrict__ counter,  // [1], zeroed
        float* __restrict__ out)             // [2]
{
    __shared__ unsigned char hist8[64 * 260];   // 16640 B, per-lane rows
    const int tid = threadIdx.x;

    // zero: word j*64+tid -> bank tid%32, 2-way, free
    unsigned int* hw = reinterpret_cast<unsigned int*>(hist8);
    #pragma unroll
    for (int j = 0; j < 65; ++j) hw[j * 64 + tid] = 0u;
    __syncthreads();

    const int batch = blockIdx.y;
    const float4* a4 = reinterpret_cast<const float4*>(ytrue + (size_t)batch * V_PER_BATCH);
    const float4* b4 = reinterpret_cast<const float4*>(ypred + (size_t)batch * V_PER_BATCH);

    const int st = BPB * 64;                  // 65536 float4s
    const int i0 = blockIdx.x * 64 + tid;     // n4 = 524288 = 8 * st

    unsigned char* hrow = hist8 + tid * 260;

    float4 A0 = a4[i0],      B0 = b4[i0];
    float4 A1 = a4[i0 + st], B1 = b4[i0 + st];

    #pragma unroll 2
    for (int it = 0; it < 8; ++it) {
        const int ipf = i0 + ((it + 2) & 7) * st;   // wraps harmlessly at tail
        float4 A2 = a4[ipf], B2 = b4[ipf];

        const float ax[4] = {A0.x, A0.y, A0.z, A0.w};
        const float bx[4] = {B0.x, B0.y, B0.z, B0.w};
        #pragma unroll
        for (int e = 0; e < 4; ++e) {
            // nearest bin: x in [0,1) -> round(15x) in 0..15
            int ca = (int)(ax[e] * 15.0f + 0.5f);
            int cb = (int)(bx[e] * 15.0f + 0.5f);
            int cell = ca * NBINS + cb;
            hrow[cell] = (unsigned char)(hrow[cell] + 1u);   // private, race-free
        }
        A0 = A1; B0 = B1; A1 = A2; B1 = B2;
    }
    __syncthreads();

    // reduce: thread t owns u32 word t (cells 4t..4t+3); sum over 64 lanes.
    // addr = l*65 + t -> bank (l+t)%32, 2-way, free. Coalesced-rate DS.
    unsigned s0 = 0, s1 = 0, s2 = 0, s3 = 0;
    #pragma unroll 8
    for (int l = 0; l < 64; ++l) {
        unsigned v = hw[l * ROWW + tid];
        s0 += v & 0xFFu;
        s1 += (v >> 8) & 0xFFu;
        s2 += (v >> 16) & 0xFFu;
        s3 += v >> 24;
    }
    const int rep = blockIdx.x & (NREP - 1);
    unsigned int* g = &ghist[(rep * 2 + batch) * NB2 + 4 * tid];
    atomicAdd(g + 0, s0);
    atomicAdd(g + 1, s1);
    atomicAdd(g + 2, s2);
    atomicAdd(g + 3, s3);

    // last-block-done: final arriver computes entropies
    __threadfence();
    __shared__ int is_last;
    if (tid == 0) {
        unsigned prev = atomicAdd(counter, 1u);
        is_last = (prev == (unsigned)(TOTAL_BLOCKS - 1));
    }
    __syncthreads();
    if (!is_last) return;
    __threadfence();

    __shared__ float pab[NB2];
    __shared__ float red[64];
    __shared__ float hx[NBINS], hy[NBINS];
    const float toP = 1.0f / (float)V_PER_BATCH;

    for (int b = 0; b < 2; ++b) {
        float rsum = 0.0f;
        #pragma unroll
        for (int r = 0; r < 4; ++r) {
            const int bin = tid + r * 64;
            unsigned v = 0;
            #pragma unroll
            for (int rp = 0; rp < NREP; ++rp)
                v += __hip_atomic_load(&ghist[(rp * 2 + b) * NB2 + bin],
                                       __ATOMIC_RELAXED, __HIP_MEMORY_SCOPE_AGENT);
            float p = (float)v * toP;
            pab[bin] = p;
            rsum += p * log2f(p + EPSF);
        }
        red[tid] = rsum;
        __syncthreads();
        for (int s = 32; s > 0; s >>= 1) {
            if (tid < s) red[tid] += red[tid + s];
            __syncthreads();
        }

        if (tid < NBINS) {
            float pa = 0.0f, pb = 0.0f;
            #pragma unroll
            for (int j = 0; j < NBINS; ++j) {
                pa += pab[tid * NBINS + j];
                pb += pab[j * NBINS + tid];
            }
            hx[tid] = pa * log2f(pa + EPSF);
            hy[tid] = pb * log2f(pb + EPSF);
        }
        __syncthreads();

        if (tid == 0) {
            float Hxy = -red[0];
            float Hx = 0.0f, Hy = 0.0f;
            #pragma unroll
            for (int i2 = 0; i2 < NBINS; ++i2) { Hx += hx[i2]; Hy += hy[i2]; }
            Hx = -Hx; Hy = -Hy;
            float nmi = 2.0f * (1.0f - Hxy / (Hx + Hy));
            out[b] = 1.0f - nmi;
        }
        __syncthreads();
    }
}

extern "C" void kernel_launch(void* const* d_in, const int* in_sizes, int n_in,
                              void* d_out, int out_size, void* d_ws, size_t ws_size,
                              hipStream_t stream) {
    const float* ytrue = (const float*)d_in[0];
    const float* ypred = (const float*)d_in[1];
    float* out = (float*)d_out;

    unsigned int* ghist   = (unsigned int*)d_ws;                   // 8*2*256*4B = 16 KB
    unsigned int* counter = (unsigned int*)((char*)d_ws + 16384);  // 4 B

    hipMemsetAsync(d_ws, 0, 16384 + 64, stream);

    dim3 grid(BPB, 2);
    nmi_hist<<<grid, 64, 0, stream>>>(ytrue, ypred, ghist, counter, out);
}